// Round 23
// baseline (218.263 us; speedup 1.0000x reference)
//
#include <hip/hip_runtime.h>
#include <hip/hip_bf16.h>

typedef _Float16 f16;
typedef __attribute__((ext_vector_type(4))) _Float16 f16x4;
typedef __attribute__((ext_vector_type(8))) _Float16 f16x8;
typedef __attribute__((ext_vector_type(4))) float f32x4;

#define DIM 1024
#define SEQ 4096
#define KRNK 256
#define NH 16
#define HD 64
#define NB 4
#define ROWS (NB*SEQ)   // 16384
#define NSPLIT 2

typedef const void __attribute__((address_space(1))) as1cv;
typedef void __attribute__((address_space(3))) as3v;

static __device__ __forceinline__ void glds16(const void* g, void* l) {
  __builtin_amdgcn_global_load_lds((as1cv*)g, (as3v*)l, 16, 0, 0);
}

// ---------------- merged prep: [0,1024) W-transpose; [1024,5120) x tsplit; [5120,5376) E ----
__global__ __launch_bounds__(256) void k_prep_all(const float* __restrict__ Wqkv,
                                                  const float* __restrict__ Wout,
                                                  const float* __restrict__ x,
                                                  const float* __restrict__ E,
                                                  f16* __restrict__ Wph,
                                                  f16* __restrict__ Wpl,
                                                  f16* __restrict__ WoT,
                                                  f16* __restrict__ xh,
                                                  f16* __restrict__ xth,
                                                  f16* __restrict__ Eth) {
  __shared__ __align__(16) float arena[64][65];   // 16.6 KB (f32 tile or f16 tileT)
  int bx = blockIdx.x;
  int t = threadIdx.x;

  if (bx < 1024) {
    const float* in; f16* oh; f16* ol; int C; bool split;
    if (bx < 768) { in = Wqkv; oh = Wph; ol = Wpl; C = 3 * DIM; split = true; }
    else { bx -= 768; in = Wout; oh = WoT; ol = nullptr; C = DIM; split = false; }
    int rt = bx & 15, ct = bx >> 4;
    int r0 = rt << 6, c0 = ct << 6;
#pragma unroll
    for (int i = 0; i < 16; ++i) {
      int e = t + i * 256; int r = e >> 6, c = e & 63;
      arena[r][c] = in[(size_t)(r0 + r) * C + c0 + c];
    }
    __syncthreads();
#pragma unroll
    for (int i = 0; i < 16; ++i) {
      int e = t + i * 256; int c = e >> 6, r = e & 63;
      float v = arena[r][c];
      size_t idx = (size_t)(c0 + c) * DIM + r0 + r;
      if (split) {
        v *= 256.0f;
        f16 h = (f16)v;
        oh[idx] = h;
        ol[idx] = (f16)(v - (float)h);
      } else {
        oh[idx] = (f16)v;
      }
    }
  } else {
    const float* in; f16* oh; f16* oth; int R, C;
    if (bx < 5120) { bx -= 1024; in = x; oh = xh; oth = xth; R = ROWS; C = DIM; }
    else { bx -= 5120; in = E; oh = nullptr; oth = Eth; R = SEQ; C = KRNK; }
    f16 (*tileT)[66] = (f16(*)[66])arena;
    int rtiles = R >> 6;
    int rt = bx % rtiles, ct = bx / rtiles;
    int r0 = rt << 6, c0 = ct << 6;
    int cq = (t & 15) * 4, rr = t >> 4;
#pragma unroll
    for (int i = 0; i < 4; ++i) {
      int r = rr + i * 16;
      f32x4 v = *(const f32x4*)&in[(size_t)(r0 + r) * C + c0 + cq];
      f16x4 h4 = {(f16)v[0], (f16)v[1], (f16)v[2], (f16)v[3]};
      if (oh) *(f16x4*)&oh[(size_t)(r0 + r) * C + c0 + cq] = h4;
#pragma unroll
      for (int k = 0; k < 4; ++k) tileT[cq + k][r] = h4[k];
    }
    __syncthreads();
    int c = t >> 2, seg = t & 3;
    f16x8 a = *(const f16x8*)&tileT[c][seg * 16];
    f16x8 b = *(const f16x8*)&tileT[c][seg * 16 + 8];
    f16* dst = &oth[(size_t)(c0 + c) * R + r0 + seg * 16];
    *(f16x8*)dst = a;
    *(f16x8*)(dst + 8) = b;
  }
}

// ---------------- generic MTxNT fp16 MFMA core, BK=64, 4 waves (2x2), single-buffer ----
// LDS slot XOR-swizzle (both sides): LDS[row][slot] = G[row][slot ^ (row&7)].
template<bool ASPL, bool BSPL, int MT, int NT>
static __device__ __forceinline__ void mm_core(
    const f16* __restrict__ Ah, const f16* __restrict__ Al, int lda,
    const f16* __restrict__ Bh, const f16* __restrict__ Bl, int ldb,
    int bm, int bn, int K,
    f16* sAh, f16* sAl, f16* sBh, f16* sBl,
    f32x4 (&acc)[MT / 32][NT / 32]) {
  constexpr int MREP = MT / 32, NREP = NT / 32;
  constexpr int AI = MT / 32, BI = NT / 32;
  const int t = threadIdx.x;
  const int lane = t & 63, w = t >> 6;
  const int wr = w >> 1, wc = w & 1;
  const int l15 = lane & 15, hi = lane >> 4;
  const f32x4 zero = {0.f, 0.f, 0.f, 0.f};
#pragma unroll
  for (int m = 0; m < MREP; ++m)
#pragma unroll
    for (int n = 0; n < NREP; ++n) acc[m][n] = zero;

  for (int kk = 0; kk < K; kk += 64) {
#pragma unroll
    for (int i = 0; i < AI; ++i) {
      int c = t + i * 256;
      int row = c >> 3, cc = c & 7;
      size_t g = (size_t)(bm + row) * lda + kk + ((cc ^ (row & 7)) * 8);
      glds16(Ah + g, &sAh[c * 8]);
      if constexpr (ASPL) glds16(Al + g, &sAl[c * 8]);
    }
#pragma unroll
    for (int i = 0; i < BI; ++i) {
      int c = t + i * 256;
      int row = c >> 3, cc = c & 7;
      size_t g = (size_t)(bn + row) * ldb + kk + ((cc ^ (row & 7)) * 8);
      glds16(Bh + g, &sBh[c * 8]);
      if constexpr (BSPL) glds16(Bl + g, &sBl[c * 8]);
    }
    __syncthreads();

    f16x8 avh[MREP][2], avl[MREP][2], bvh[NREP][2], bvl[NREP][2];
#pragma unroll
    for (int m = 0; m < MREP; ++m)
#pragma unroll
      for (int ks = 0; ks < 2; ++ks) {
        int R = wr * (MT / 2) + m * 16 + l15;
        int off = R * 64 + (((ks * 4 + hi) ^ (R & 7)) * 8);
        avh[m][ks] = *(const f16x8*)&sAh[off];
        if constexpr (ASPL) avl[m][ks] = *(const f16x8*)&sAl[off];
      }
#pragma unroll
    for (int n = 0; n < NREP; ++n)
#pragma unroll
      for (int ks = 0; ks < 2; ++ks) {
        int R = wc * (NT / 2) + n * 16 + l15;
        int off = R * 64 + (((ks * 4 + hi) ^ (R & 7)) * 8);
        bvh[n][ks] = *(const f16x8*)&sBh[off];
        if constexpr (BSPL) bvl[n][ks] = *(const f16x8*)&sBl[off];
      }
#pragma unroll
    for (int m = 0; m < MREP; ++m)
#pragma unroll
      for (int n = 0; n < NREP; ++n)
#pragma unroll
        for (int ks = 0; ks < 2; ++ks) {
          if constexpr (ASPL && BSPL) {
            acc[m][n] = __builtin_amdgcn_mfma_f32_16x16x32_f16(avl[m][ks], bvh[n][ks], acc[m][n], 0, 0, 0);
            acc[m][n] = __builtin_amdgcn_mfma_f32_16x16x32_f16(avh[m][ks], bvl[n][ks], acc[m][n], 0, 0, 0);
          } else if constexpr (BSPL) {
            acc[m][n] = __builtin_amdgcn_mfma_f32_16x16x32_f16(avh[m][ks], bvl[n][ks], acc[m][n], 0, 0, 0);
          }
          acc[m][n] = __builtin_amdgcn_mfma_f32_16x16x32_f16(avh[m][ks], bvh[n][ks], acc[m][n], 0, 0, 0);
        }
    __syncthreads();
  }
}

// ---------------- merged mid: [0,256) XE partials (split-K x2); [256,1280) GQ ----------------
// xe2 blocks dispatch first (start at t=0); gq's 1024 blocks supply CU-level TLP, so
// NSPLIT=2 (32 K-iters/block, ~55us critical path) fits under gq's bulk while halving
// XEp partial traffic vs NSPLIT=4.
__global__ __launch_bounds__(256) void k_mid(const f16* __restrict__ Eth,
                                             const f16* __restrict__ xth,
                                             float* __restrict__ XEp,
                                             const f16* __restrict__ xh,
                                             const f16* __restrict__ Wph,
                                             f16* __restrict__ q) {
  __shared__ __align__(16) f16 arena[2 * 128 * 64];   // 32 KB
  f16* sA = arena;
  f16* sB = arena + 128 * 64;
  int bx = blockIdx.x;
  const int t = threadIdx.x, lane = t & 63, w = t >> 6;
  const int wr = w >> 1, wc = w & 1, l15 = lane & 15, hi = lane >> 4;

  if (bx < 256) {
    // ---- XE partials: 1-term fp16 GEMM, split-K x2 ----
    int nt = bx & 15, mt = (bx >> 4) & 1, b = (bx >> 5) & 3, sp = (bx >> 7) & 1;
    int bm = mt << 7, bn = nt << 6;
    int koff = sp * (SEQ / NSPLIT);
    f32x4 acc[4][2];
    mm_core<false, false, 128, 64>(Eth + koff, nullptr, SEQ,
                                   xth + (size_t)b * SEQ + koff, nullptr, ROWS,
                                   bm, bn, SEQ / NSPLIT, sA, nullptr, sB, nullptr, acc);
#pragma unroll
    for (int m = 0; m < 4; ++m)
#pragma unroll
      for (int n = 0; n < 2; ++n)
#pragma unroll
        for (int r = 0; r < 4; ++r) {
          int kr = bm + wr * 64 + m * 16 + hi * 4 + r;
          int dd = bn + wc * 32 + n * 16 + l15;
          XEp[(((size_t)sp * NB + b) * KRNK + kr) * DIM + dd] = acc[m][n][r];
        }
  } else {
    // ---- GQ: q = xh @ Wqh, 128x128 tiles, mt-fast ----
    bx -= 256;
    int mt = bx & 127, nt = bx >> 7;
    int bm = mt << 7, bn = nt << 7;
    f32x4 acc[4][4];
    mm_core<false, false, 128, 128>(xh, nullptr, DIM, Wph, nullptr, DIM, bm, bn, DIM,
                                    sA, nullptr, sB, nullptr, acc);
#pragma unroll
    for (int m = 0; m < 4; ++m)
#pragma unroll
      for (int n = 0; n < 4; ++n)
#pragma unroll
        for (int r = 0; r < 4; ++r) {
          int row = bm + wr * 64 + m * 16 + hi * 4 + r;
          int col = bn + wc * 64 + n * 16 + l15;
          q[(size_t)row * DIM + col] = (f16)(acc[m][n][r] * (1.0f / 256.0f));
        }
  }
}

// ---------------- XE reduce: sum 2 partials, single f16 out ----------------
__global__ __launch_bounds__(256) void k_xered(const float* __restrict__ XEp,
                                               f16* __restrict__ XEh) {
  size_t i = (size_t)blockIdx.x * 256 + threadIdx.x;   // f32x4 index
  const size_t sstride = (size_t)NB * KRNK * DIM / 4;
  const f32x4* p = (const f32x4*)XEp;
  f32x4 s = p[i];
#pragma unroll
  for (int sp = 1; sp < NSPLIT; ++sp) s += p[i + sp * sstride];
  f16x4 h4 = {(f16)s[0], (f16)s[1], (f16)s[2], (f16)s[3]};
  *(f16x4*)&XEh[i * 4] = h4;
}

// ---------------- T2: kp/vp = XEh @ (W{k,v}h+l)  (2 terms) ----------------
__global__ __launch_bounds__(256) void k_t2(const f16* __restrict__ XEh,
                                            const f16* __restrict__ Wph,
                                            const f16* __restrict__ Wpl,
                                            f16* __restrict__ kph,
                                            f16* __restrict__ vpt) {
  __shared__ __align__(16) f16 sAh[128 * 64];
  __shared__ __align__(16) f16 sBh[64 * 64], sBl[64 * 64];
  int bx = blockIdx.x;                       // 256: nt(16) x mt(2) x b(4) x kv(2)
  int nt = bx & 15, mt = (bx >> 4) & 1, b = (bx >> 5) & 3, kv = bx >> 7;
  size_t abase = (size_t)b * KRNK * DIM;
  size_t wbase = (size_t)(DIM + kv * DIM) * DIM;
  f32x4 acc[4][2];
  mm_core<false, true, 128, 64>(XEh + abase, nullptr, DIM, Wph + wbase, Wpl + wbase, DIM,
                                mt << 7, nt << 6, DIM, sAh, nullptr, sBh, sBl, acc);
  const int t = threadIdx.x, lane = t & 63, w = t >> 6;
  const int wr = w >> 1, wc = w & 1, l15 = lane & 15, hi = lane >> 4;
#pragma unroll
  for (int m = 0; m < 4; ++m)
#pragma unroll
    for (int n = 0; n < 2; ++n)
#pragma unroll
      for (int r = 0; r < 4; ++r) {
        int row = (mt << 7) + wr * 64 + m * 16 + hi * 4 + r;   // kr
        int col = (nt << 6) + wc * 32 + n * 16 + l15;          // dd
        float s = acc[m][n][r] * (1.0f / 256.0f);
        if (!kv) kph[((size_t)(b * KRNK + row)) * DIM + col] = (f16)s;
        else     vpt[((size_t)(b * DIM + col)) * KRNK + row] = (f16)s;
      }
}

// ---------------- fused attention: KBLK=128 (4 barriers), swapped S^T, lane-local softmax ----
__global__ __launch_bounds__(256) void k_attn(const f16* __restrict__ q,
                                              const f16* __restrict__ kph,
                                              const f16* __restrict__ vpt,
                                              f16* __restrict__ oattn) {
  __shared__ __align__(16) f16 sBuf[2][128 * 64];  // 2 x 16 KB staging
  __shared__ __align__(16) f16 sP[64 * KRNK];      // 32 KB
  int bx0 = blockIdx.x;
  int swz = (bx0 & 7) * 512 + (bx0 >> 3);          // XCD-contiguous (4096 % 8 == 0)
  int qb = swz & 63;
  int bh = swz >> 6;
  int b = bh >> 4, h = bh & 15;
  int t = threadIdx.x;
  int lane = t & 63, w = t >> 6;
  int l15 = lane & 15, hi = lane >> 4;

  const f16* kbase = kph + ((size_t)(b * KRNK)) * DIM + h * HD;
  const f16* vbase = vpt + ((size_t)(b * DIM + h * HD)) * KRNK;

  auto stageK = [&](int c, int bufi) {
#pragma unroll
    for (int i = 0; i < 4; ++i) {
      int c2 = t + i * 256;
      int kr = c2 >> 3, sl = c2 & 7;
      glds16(kbase + (size_t)(c * 128 + kr) * DIM + ((sl ^ (kr & 7)) * 8),
             &sBuf[bufi][c2 * 8]);
    }
  };
  auto stageV = [&](int c, int bufi) {
#pragma unroll
    for (int i = 0; i < 4; ++i) {
      int c2 = t + i * 256;
      int hd = c2 >> 4, sl = c2 & 15;
      glds16(vbase + (size_t)hd * KRNK + c * 128 + ((sl ^ (hd & 7)) * 8),
             &sBuf[bufi][c2 * 8]);
    }
  };

  int seqrow = qb * 64 + w * 16 + l15;
  const f16* qg = q + ((size_t)(b * SEQ + seqrow)) * DIM + h * HD;
  f16x8 aq[2];
  aq[0] = *(const f16x8*)(qg + hi * 8);
  aq[1] = *(const f16x8*)(qg + 32 + hi * 8);

  const f32x4 zero = {0.f, 0.f, 0.f, 0.f};
  f32x4 s[16];

  stageK(0, 0);
#pragma unroll
  for (int c = 0; c < 2; ++c) {
    __syncthreads();
    if (c == 0) stageK(1, 1);
    else        stageV(0, 0);
#pragma unroll
    for (int n = 0; n < 8; ++n) {
      int nn = c * 8 + n;
      s[nn] = zero;
      int krl = n * 16 + l15;
#pragma unroll
      for (int ks = 0; ks < 2; ++ks) {
        f16x8 bk = *(const f16x8*)&sBuf[c][krl * 64 + (((ks * 4 + hi) ^ (krl & 7)) * 8)];
        s[nn] = __builtin_amdgcn_mfma_f32_16x16x32_f16(bk, aq[ks], s[nn], 0, 0, 0);  // SWAPPED
      }
    }
  }

  const float scale = 0.125f;
  float m0 = s[0][0];
#pragma unroll
  for (int n = 0; n < 16; ++n)
#pragma unroll
    for (int r = 0; r < 4; ++r) m0 = fmaxf(m0, s[n][r]);
  m0 = fmaxf(m0, __shfl_xor(m0, 16));
  m0 = fmaxf(m0, __shfl_xor(m0, 32));
  float sm0 = 0.f, sm1 = 0.f, sm2 = 0.f, sm3 = 0.f;
#pragma unroll
  for (int n = 0; n < 16; ++n) {
    float p0 = __expf((s[n][0] - m0) * scale);
    float p1 = __expf((s[n][1] - m0) * scale);
    float p2 = __expf((s[n][2] - m0) * scale);
    float p3 = __expf((s[n][3] - m0) * scale);
    s[n][0] = p0; s[n][1] = p1; s[n][2] = p2; s[n][3] = p3;
    sm0 += p0; sm1 += p1; sm2 += p2; sm3 += p3;
  }
  float sm = (sm0 + sm1) + (sm2 + sm3);
  sm += __shfl_xor(sm, 16);
  sm += __shfl_xor(sm, 32);
  float inv = 1.0f / sm;

  {
    int qrow = w * 16 + l15;
    int qm = qrow & 7;
    f16* rowp = &sP[qrow * KRNK];
#pragma unroll
    for (int n = 0; n < 16; ++n) {
      int chunk = 2 * n + (hi >> 1);
      f16x4 pv = {(f16)s[n][0], (f16)s[n][1], (f16)s[n][2], (f16)s[n][3]};
      *(f16x4*)&rowp[((chunk ^ qm) * 8) + (hi & 1) * 4] = pv;
    }
  }

  f32x4 o[4];
#pragma unroll
  for (int n = 0; n < 4; ++n) o[n] = zero;
  int qloc = w * 16 + l15;
#pragma unroll
  for (int c = 0; c < 2; ++c) {
    __syncthreads();
    if (c == 0) stageV(1, 1);
#pragma unroll
    for (int q4 = 0; q4 < 4; ++q4) {
      int chunk = c * 16 + q4 * 4 + hi;
      f16x8 pa = *(const f16x8*)&sP[qloc * KRNK + ((chunk ^ (qloc & 7)) * 8)];
#pragma unroll
      for (int n = 0; n < 4; ++n) {
        int hd = n * 16 + l15;
        f16x8 bv = *(const f16x8*)&sBuf[c][hd * 128 + (((q4 * 4 + hi) ^ (hd & 7)) * 8)];
        o[n] = __builtin_amdgcn_mfma_f32_16x16x32_f16(pa, bv, o[n], 0, 0, 0);
      }
    }
  }

  float invr[4];
#pragma unroll
  for (int r = 0; r < 4; ++r) invr[r] = __shfl(inv, hi * 4 + r);

  size_t obase = ((size_t)(b * SEQ + qb * 64)) * DIM + h * HD;
#pragma unroll
  for (int n = 0; n < 4; ++n)
#pragma unroll
    for (int r = 0; r < 4; ++r) {
      int qloc2 = w * 16 + hi * 4 + r;
      int hd = n * 16 + l15;
      oattn[obase + (size_t)qloc2 * DIM + hd] = (f16)(o[n][r] * invr[r]);
    }
}

// ---------------- GO: out = oattn @ W_out + b_out, 128x128 tiles (fp32 out) ----------------
__global__ __launch_bounds__(256) void k_go(const f16* __restrict__ oattn,
                                            const f16* __restrict__ WoT,
                                            const float* __restrict__ bias,
                                            float* __restrict__ out) {
  __shared__ __align__(16) f16 sA[128 * 64];
  __shared__ __align__(16) f16 sB[128 * 64];
  int bx = blockIdx.x;                 // 1024: mt(128) x nt(8)
  int mt = bx & 127, nt = bx >> 7;
  int bm = mt << 7, bn = nt << 7;
  f32x4 acc[4][4];
  mm_core<false, false, 128, 128>(oattn, nullptr, DIM, WoT, nullptr, DIM, bm, bn, DIM,
                                  sA, nullptr, sB, nullptr, acc);
  const int t = threadIdx.x, lane = t & 63, w = t >> 6;
  const int wr = w >> 1, wc = w & 1, l15 = lane & 15, hi = lane >> 4;
#pragma unroll
  for (int m = 0; m < 4; ++m)
#pragma unroll
    for (int n = 0; n < 4; ++n)
#pragma unroll
      for (int r = 0; r < 4; ++r) {
        int row = bm + wr * 64 + m * 16 + hi * 4 + r;
        int col = bn + wc * 64 + n * 16 + l15;
        out[(size_t)row * DIM + col] = acc[m][n][r] + bias[col];
      }
}

extern "C" void kernel_launch(void* const* d_in, const int* in_sizes, int n_in,
                              void* d_out, int out_size, void* d_ws, size_t ws_size,
                              hipStream_t stream) {
  const float* x    = (const float*)d_in[0];
  const float* Wqkv = (const float*)d_in[1];
  const float* E    = (const float*)d_in[2];
  const float* Wout = (const float*)d_in[3];
  const float* bout = (const float*)d_in[4];
  float* out = (float*)d_out;

  char* p = (char*)d_ws;
  f16* Wph = (f16*)p;  p += (size_t)2 * 3 * DIM * DIM;   //  6.29 MB
  f16* Wpl = (f16*)p;  p += (size_t)2 * 3 * DIM * DIM;
  f16* WoT = (f16*)p;  p += (size_t)2 * DIM * DIM;
  f16* xh  = (f16*)p;  p += (size_t)2 * ROWS * DIM;      // 33.55 MB
  f16* xth = (f16*)p;  p += (size_t)2 * DIM * ROWS;      // 33.55 MB
  f16* q   = (f16*)p;  p += (size_t)2 * ROWS * DIM;      // 33.55 MB
  f16* Eth = (f16*)p;  p += (size_t)2 * KRNK * SEQ;
  f16* XEh = (f16*)p;  p += (size_t)2 * NB * KRNK * DIM;
  f16* kph = (f16*)p;  p += (size_t)2 * NB * KRNK * DIM;
  f16* vpt = (f16*)p;  p += (size_t)2 * NB * DIM * KRNK;
  f16* oattn = (f16*)p; p += (size_t)2 * ROWS * DIM;     // 33.55 MB
  float* XEp = (float*)p;  p += (size_t)4 * NSPLIT * NB * KRNK * DIM;  // 8.4 MB
  size_t need = (size_t)(p - (char*)d_ws);
  if (ws_size < need) return;

  // grid = 1024 (W) + 4096 (x: 256 rtiles x 16 ctiles) + 256 (E: 64 rtiles x 4 ctiles)
  k_prep_all<<<5376, 256, 0, stream>>>(Wqkv, Wout, x, E, Wph, Wpl, WoT, xh, xth, Eth);
  k_mid<<<1280, 256, 0, stream>>>(Eth, xth, XEp, xh, Wph, q);
  k_xered<<<(NB * KRNK * DIM / 4) / 256, 256, 0, stream>>>(XEp, XEh);
  k_t2<<<256, 256, 0, stream>>>(XEh, Wph, Wpl, kph, vpt);
  k_attn<<<64 * 64, 256, 0, stream>>>(q, kph, vpt, oattn);
  k_go<<<1024, 256, 0, stream>>>(oattn, WoT, bout, out);
}

// Round 24
// 214.056 us; speedup vs baseline: 1.0197x; 1.0197x over previous
//
#include <hip/hip_runtime.h>
#include <hip/hip_bf16.h>

typedef _Float16 f16;
typedef __attribute__((ext_vector_type(4))) _Float16 f16x4;
typedef __attribute__((ext_vector_type(8))) _Float16 f16x8;
typedef __attribute__((ext_vector_type(4))) float f32x4;

#define DIM 1024
#define SEQ 4096
#define KRNK 256
#define NH 16
#define HD 64
#define NB 4
#define ROWS (NB*SEQ)   // 16384
#define NSPLIT 4

typedef const void __attribute__((address_space(1))) as1cv;
typedef void __attribute__((address_space(3))) as3v;

static __device__ __forceinline__ void glds16(const void* g, void* l) {
  __builtin_amdgcn_global_load_lds((as1cv*)g, (as3v*)l, 16, 0, 0);
}

// ---------------- merged prep: [0,1024) W-transpose; [1024,5120) x tsplit; [5120,5376) E ----
__global__ __launch_bounds__(256) void k_prep_all(const float* __restrict__ Wqkv,
                                                  const float* __restrict__ Wout,
                                                  const float* __restrict__ x,
                                                  const float* __restrict__ E,
                                                  f16* __restrict__ Wph,
                                                  f16* __restrict__ Wpl,
                                                  f16* __restrict__ WoT,
                                                  f16* __restrict__ xh,
                                                  f16* __restrict__ xth,
                                                  f16* __restrict__ Eth) {
  __shared__ __align__(16) float arena[64][65];   // 16.6 KB (f32 tile or f16 tileT)
  int bx = blockIdx.x;
  int t = threadIdx.x;

  if (bx < 1024) {
    // ---- W prep (transpose f32 -> f16; Wqkv scaled x256 h/l, Wout single) ----
    const float* in; f16* oh; f16* ol; int C; bool split;
    if (bx < 768) { in = Wqkv; oh = Wph; ol = Wpl; C = 3 * DIM; split = true; }
    else { bx -= 768; in = Wout; oh = WoT; ol = nullptr; C = DIM; split = false; }
    int rt = bx & 15, ct = bx >> 4;
    int r0 = rt << 6, c0 = ct << 6;
#pragma unroll
    for (int i = 0; i < 16; ++i) {
      int e = t + i * 256; int r = e >> 6, c = e & 63;
      arena[r][c] = in[(size_t)(r0 + r) * C + c0 + c];
    }
    __syncthreads();
#pragma unroll
    for (int i = 0; i < 16; ++i) {
      int e = t + i * 256; int c = e >> 6, r = e & 63;
      float v = arena[r][c];
      size_t idx = (size_t)(c0 + c) * DIM + r0 + r;
      if (split) {
        v *= 256.0f;
        f16 h = (f16)v;
        oh[idx] = h;
        ol[idx] = (f16)(v - (float)h);
      } else {
        oh[idx] = (f16)v;
      }
    }
  } else {
    // ---- tsplit: f32 [R][C] -> f16 transpose (and opt f16 copy) ----
    const float* in; f16* oh; f16* oth; int R, C;
    if (bx < 5120) { bx -= 1024; in = x; oh = xh; oth = xth; R = ROWS; C = DIM; }
    else { bx -= 5120; in = E; oh = nullptr; oth = Eth; R = SEQ; C = KRNK; }
    f16 (*tileT)[66] = (f16(*)[66])arena;
    int rtiles = R >> 6;
    int rt = bx % rtiles, ct = bx / rtiles;
    int r0 = rt << 6, c0 = ct << 6;
    int cq = (t & 15) * 4, rr = t >> 4;
#pragma unroll
    for (int i = 0; i < 4; ++i) {
      int r = rr + i * 16;
      f32x4 v = *(const f32x4*)&in[(size_t)(r0 + r) * C + c0 + cq];
      f16x4 h4 = {(f16)v[0], (f16)v[1], (f16)v[2], (f16)v[3]};
      if (oh) *(f16x4*)&oh[(size_t)(r0 + r) * C + c0 + cq] = h4;
#pragma unroll
      for (int k = 0; k < 4; ++k) tileT[cq + k][r] = h4[k];
    }
    __syncthreads();
    int c = t >> 2, seg = t & 3;
    f16x8 a = *(const f16x8*)&tileT[c][seg * 16];
    f16x8 b = *(const f16x8*)&tileT[c][seg * 16 + 8];
    f16* dst = &oth[(size_t)(c0 + c) * R + r0 + seg * 16];
    *(f16x8*)dst = a;
    *(f16x8*)(dst + 8) = b;
  }
}

// ---------------- generic MTxNT fp16 MFMA core, BK=64, 4 waves (2x2), single-buffer ----
// LDS slot XOR-swizzle (both sides): LDS[row][slot] = G[row][slot ^ (row&7)].
template<bool ASPL, bool BSPL, int MT, int NT>
static __device__ __forceinline__ void mm_core(
    const f16* __restrict__ Ah, const f16* __restrict__ Al, int lda,
    const f16* __restrict__ Bh, const f16* __restrict__ Bl, int ldb,
    int bm, int bn, int K,
    f16* sAh, f16* sAl, f16* sBh, f16* sBl,
    f32x4 (&acc)[MT / 32][NT / 32]) {
  constexpr int MREP = MT / 32, NREP = NT / 32;
  constexpr int AI = MT / 32, BI = NT / 32;
  const int t = threadIdx.x;
  const int lane = t & 63, w = t >> 6;
  const int wr = w >> 1, wc = w & 1;
  const int l15 = lane & 15, hi = lane >> 4;
  const f32x4 zero = {0.f, 0.f, 0.f, 0.f};
#pragma unroll
  for (int m = 0; m < MREP; ++m)
#pragma unroll
    for (int n = 0; n < NREP; ++n) acc[m][n] = zero;

  for (int kk = 0; kk < K; kk += 64) {
#pragma unroll
    for (int i = 0; i < AI; ++i) {
      int c = t + i * 256;
      int row = c >> 3, cc = c & 7;
      size_t g = (size_t)(bm + row) * lda + kk + ((cc ^ (row & 7)) * 8);
      glds16(Ah + g, &sAh[c * 8]);
      if constexpr (ASPL) glds16(Al + g, &sAl[c * 8]);
    }
#pragma unroll
    for (int i = 0; i < BI; ++i) {
      int c = t + i * 256;
      int row = c >> 3, cc = c & 7;
      size_t g = (size_t)(bn + row) * ldb + kk + ((cc ^ (row & 7)) * 8);
      glds16(Bh + g, &sBh[c * 8]);
      if constexpr (BSPL) glds16(Bl + g, &sBl[c * 8]);
    }
    __syncthreads();

    f16x8 avh[MREP][2], avl[MREP][2], bvh[NREP][2], bvl[NREP][2];
#pragma unroll
    for (int m = 0; m < MREP; ++m)
#pragma unroll
      for (int ks = 0; ks < 2; ++ks) {
        int R = wr * (MT / 2) + m * 16 + l15;
        int off = R * 64 + (((ks * 4 + hi) ^ (R & 7)) * 8);
        avh[m][ks] = *(const f16x8*)&sAh[off];
        if constexpr (ASPL) avl[m][ks] = *(const f16x8*)&sAl[off];
      }
#pragma unroll
    for (int n = 0; n < NREP; ++n)
#pragma unroll
      for (int ks = 0; ks < 2; ++ks) {
        int R = wc * (NT / 2) + n * 16 + l15;
        int off = R * 64 + (((ks * 4 + hi) ^ (R & 7)) * 8);
        bvh[n][ks] = *(const f16x8*)&sBh[off];
        if constexpr (BSPL) bvl[n][ks] = *(const f16x8*)&sBl[off];
      }
#pragma unroll
    for (int m = 0; m < MREP; ++m)
#pragma unroll
      for (int n = 0; n < NREP; ++n)
#pragma unroll
        for (int ks = 0; ks < 2; ++ks) {
          if constexpr (ASPL && BSPL) {
            acc[m][n] = __builtin_amdgcn_mfma_f32_16x16x32_f16(avl[m][ks], bvh[n][ks], acc[m][n], 0, 0, 0);
            acc[m][n] = __builtin_amdgcn_mfma_f32_16x16x32_f16(avh[m][ks], bvl[n][ks], acc[m][n], 0, 0, 0);
          } else if constexpr (BSPL) {
            acc[m][n] = __builtin_amdgcn_mfma_f32_16x16x32_f16(avh[m][ks], bvl[n][ks], acc[m][n], 0, 0, 0);
          }
          acc[m][n] = __builtin_amdgcn_mfma_f32_16x16x32_f16(avh[m][ks], bvh[n][ks], acc[m][n], 0, 0, 0);
        }
    __syncthreads();
  }
}

// ---------------- merged mid: [0,512) XE partials (split-K x4); [512,1536) GQ ----------------
__global__ __launch_bounds__(256) void k_mid(const f16* __restrict__ Eth,
                                             const f16* __restrict__ xth,
                                             float* __restrict__ XEp,
                                             const f16* __restrict__ xh,
                                             const f16* __restrict__ Wph,
                                             f16* __restrict__ q) {
  __shared__ __align__(16) f16 arena[2 * 128 * 64];   // 32 KB
  f16* sA = arena;
  f16* sB = arena + 128 * 64;
  int bx = blockIdx.x;
  const int t = threadIdx.x, lane = t & 63, w = t >> 6;
  const int wr = w >> 1, wc = w & 1, l15 = lane & 15, hi = lane >> 4;

  if (bx < 512) {
    // ---- XE partials: 1-term fp16 GEMM, split-K x4 ----
    int nt = bx & 15, mt = (bx >> 4) & 1, b = (bx >> 5) & 3, sp = bx >> 7;
    int bm = mt << 7, bn = nt << 6;
    int koff = sp * (SEQ / NSPLIT);
    f32x4 acc[4][2];
    mm_core<false, false, 128, 64>(Eth + koff, nullptr, SEQ,
                                   xth + (size_t)b * SEQ + koff, nullptr, ROWS,
                                   bm, bn, SEQ / NSPLIT, sA, nullptr, sB, nullptr, acc);
#pragma unroll
    for (int m = 0; m < 4; ++m)
#pragma unroll
      for (int n = 0; n < 2; ++n)
#pragma unroll
        for (int r = 0; r < 4; ++r) {
          int kr = bm + wr * 64 + m * 16 + hi * 4 + r;
          int dd = bn + wc * 32 + n * 16 + l15;
          XEp[(((size_t)sp * NB + b) * KRNK + kr) * DIM + dd] = acc[m][n][r];
        }
  } else {
    // ---- GQ: q = xh @ Wqh, 128x128 tiles, mt-fast ----
    bx -= 512;
    int mt = bx & 127, nt = bx >> 7;
    int bm = mt << 7, bn = nt << 7;
    f32x4 acc[4][4];
    mm_core<false, false, 128, 128>(xh, nullptr, DIM, Wph, nullptr, DIM, bm, bn, DIM,
                                    sA, nullptr, sB, nullptr, acc);
#pragma unroll
    for (int m = 0; m < 4; ++m)
#pragma unroll
      for (int n = 0; n < 4; ++n)
#pragma unroll
        for (int r = 0; r < 4; ++r) {
          int row = bm + wr * 64 + m * 16 + hi * 4 + r;
          int col = bn + wc * 64 + n * 16 + l15;
          q[(size_t)row * DIM + col] = (f16)(acc[m][n][r] * (1.0f / 256.0f));
        }
  }
}

// ---------------- XE reduce: sum 4 partials, single f16 out ----------------
__global__ __launch_bounds__(256) void k_xered(const float* __restrict__ XEp,
                                               f16* __restrict__ XEh) {
  size_t i = (size_t)blockIdx.x * 256 + threadIdx.x;   // f32x4 index
  const size_t sstride = (size_t)NB * KRNK * DIM / 4;
  const f32x4* p = (const f32x4*)XEp;
  f32x4 s = p[i];
#pragma unroll
  for (int sp = 1; sp < NSPLIT; ++sp) s += p[i + sp * sstride];
  f16x4 h4 = {(f16)s[0], (f16)s[1], (f16)s[2], (f16)s[3]};
  *(f16x4*)&XEh[i * 4] = h4;
}

// ---------------- T2: kp/vp = XEh @ (W{k,v}h+l)  (2 terms) ----------------
__global__ __launch_bounds__(256) void k_t2(const f16* __restrict__ XEh,
                                            const f16* __restrict__ Wph,
                                            const f16* __restrict__ Wpl,
                                            f16* __restrict__ kph,
                                            f16* __restrict__ vpt) {
  __shared__ __align__(16) f16 sAh[128 * 64];
  __shared__ __align__(16) f16 sBh[64 * 64], sBl[64 * 64];
  int bx = blockIdx.x;                       // 256: nt(16) x mt(2) x b(4) x kv(2)
  int nt = bx & 15, mt = (bx >> 4) & 1, b = (bx >> 5) & 3, kv = bx >> 7;
  size_t abase = (size_t)b * KRNK * DIM;
  size_t wbase = (size_t)(DIM + kv * DIM) * DIM;
  f32x4 acc[4][2];
  mm_core<false, true, 128, 64>(XEh + abase, nullptr, DIM, Wph + wbase, Wpl + wbase, DIM,
                                mt << 7, nt << 6, DIM, sAh, nullptr, sBh, sBl, acc);
  const int t = threadIdx.x, lane = t & 63, w = t >> 6;
  const int wr = w >> 1, wc = w & 1, l15 = lane & 15, hi = lane >> 4;
#pragma unroll
  for (int m = 0; m < 4; ++m)
#pragma unroll
    for (int n = 0; n < 2; ++n)
#pragma unroll
      for (int r = 0; r < 4; ++r) {
        int row = (mt << 7) + wr * 64 + m * 16 + hi * 4 + r;   // kr
        int col = (nt << 6) + wc * 32 + n * 16 + l15;          // dd
        float s = acc[m][n][r] * (1.0f / 256.0f);
        if (!kv) kph[((size_t)(b * KRNK + row)) * DIM + col] = (f16)s;
        else     vpt[((size_t)(b * DIM + col)) * KRNK + row] = (f16)s;
      }
}

// ---------------- fused attention: KBLK=128 (4 barriers), swapped S^T, lane-local softmax ----
__global__ __launch_bounds__(256) void k_attn(const f16* __restrict__ q,
                                              const f16* __restrict__ kph,
                                              const f16* __restrict__ vpt,
                                              f16* __restrict__ oattn) {
  __shared__ __align__(16) f16 sBuf[2][128 * 64];  // 2 x 16 KB staging
  __shared__ __align__(16) f16 sP[64 * KRNK];      // 32 KB
  int bx0 = blockIdx.x;
  int swz = (bx0 & 7) * 512 + (bx0 >> 3);          // XCD-contiguous (4096 % 8 == 0)
  int qb = swz & 63;
  int bh = swz >> 6;
  int b = bh >> 4, h = bh & 15;
  int t = threadIdx.x;
  int lane = t & 63, w = t >> 6;
  int l15 = lane & 15, hi = lane >> 4;

  const f16* kbase = kph + ((size_t)(b * KRNK)) * DIM + h * HD;
  const f16* vbase = vpt + ((size_t)(b * DIM + h * HD)) * KRNK;

  auto stageK = [&](int c, int bufi) {
#pragma unroll
    for (int i = 0; i < 4; ++i) {
      int c2 = t + i * 256;
      int kr = c2 >> 3, sl = c2 & 7;
      glds16(kbase + (size_t)(c * 128 + kr) * DIM + ((sl ^ (kr & 7)) * 8),
             &sBuf[bufi][c2 * 8]);
    }
  };
  auto stageV = [&](int c, int bufi) {
#pragma unroll
    for (int i = 0; i < 4; ++i) {
      int c2 = t + i * 256;
      int hd = c2 >> 4, sl = c2 & 15;
      glds16(vbase + (size_t)hd * KRNK + c * 128 + ((sl ^ (hd & 7)) * 8),
             &sBuf[bufi][c2 * 8]);
    }
  };

  int seqrow = qb * 64 + w * 16 + l15;
  const f16* qg = q + ((size_t)(b * SEQ + seqrow)) * DIM + h * HD;
  f16x8 aq[2];
  aq[0] = *(const f16x8*)(qg + hi * 8);
  aq[1] = *(const f16x8*)(qg + 32 + hi * 8);

  const f32x4 zero = {0.f, 0.f, 0.f, 0.f};
  f32x4 s[16];

  stageK(0, 0);
#pragma unroll
  for (int c = 0; c < 2; ++c) {
    __syncthreads();
    if (c == 0) stageK(1, 1);
    else        stageV(0, 0);
#pragma unroll
    for (int n = 0; n < 8; ++n) {
      int nn = c * 8 + n;
      s[nn] = zero;
      int krl = n * 16 + l15;
#pragma unroll
      for (int ks = 0; ks < 2; ++ks) {
        f16x8 bk = *(const f16x8*)&sBuf[c][krl * 64 + (((ks * 4 + hi) ^ (krl & 7)) * 8)];
        s[nn] = __builtin_amdgcn_mfma_f32_16x16x32_f16(bk, aq[ks], s[nn], 0, 0, 0);  // SWAPPED
      }
    }
  }

  const float scale = 0.125f;
  float m0 = s[0][0];
#pragma unroll
  for (int n = 0; n < 16; ++n)
#pragma unroll
    for (int r = 0; r < 4; ++r) m0 = fmaxf(m0, s[n][r]);
  m0 = fmaxf(m0, __shfl_xor(m0, 16));
  m0 = fmaxf(m0, __shfl_xor(m0, 32));
  float sm0 = 0.f, sm1 = 0.f, sm2 = 0.f, sm3 = 0.f;
#pragma unroll
  for (int n = 0; n < 16; ++n) {
    float p0 = __expf((s[n][0] - m0) * scale);
    float p1 = __expf((s[n][1] - m0) * scale);
    float p2 = __expf((s[n][2] - m0) * scale);
    float p3 = __expf((s[n][3] - m0) * scale);
    s[n][0] = p0; s[n][1] = p1; s[n][2] = p2; s[n][3] = p3;
    sm0 += p0; sm1 += p1; sm2 += p2; sm3 += p3;
  }
  float sm = (sm0 + sm1) + (sm2 + sm3);
  sm += __shfl_xor(sm, 16);
  sm += __shfl_xor(sm, 32);
  float inv = 1.0f / sm;

  {
    int qrow = w * 16 + l15;
    int qm = qrow & 7;
    f16* rowp = &sP[qrow * KRNK];
#pragma unroll
    for (int n = 0; n < 16; ++n) {
      int chunk = 2 * n + (hi >> 1);
      f16x4 pv = {(f16)s[n][0], (f16)s[n][1], (f16)s[n][2], (f16)s[n][3]};
      *(f16x4*)&rowp[((chunk ^ qm) * 8) + (hi & 1) * 4] = pv;
    }
  }

  f32x4 o[4];
#pragma unroll
  for (int n = 0; n < 4; ++n) o[n] = zero;
  int qloc = w * 16 + l15;
#pragma unroll
  for (int c = 0; c < 2; ++c) {
    __syncthreads();
    if (c == 0) stageV(1, 1);
#pragma unroll
    for (int q4 = 0; q4 < 4; ++q4) {
      int chunk = c * 16 + q4 * 4 + hi;
      f16x8 pa = *(const f16x8*)&sP[qloc * KRNK + ((chunk ^ (qloc & 7)) * 8)];
#pragma unroll
      for (int n = 0; n < 4; ++n) {
        int hd = n * 16 + l15;
        f16x8 bv = *(const f16x8*)&sBuf[c][hd * 128 + (((q4 * 4 + hi) ^ (hd & 7)) * 8)];
        o[n] = __builtin_amdgcn_mfma_f32_16x16x32_f16(pa, bv, o[n], 0, 0, 0);
      }
    }
  }

  float invr[4];
#pragma unroll
  for (int r = 0; r < 4; ++r) invr[r] = __shfl(inv, hi * 4 + r);

  size_t obase = ((size_t)(b * SEQ + qb * 64)) * DIM + h * HD;
#pragma unroll
  for (int n = 0; n < 4; ++n)
#pragma unroll
    for (int r = 0; r < 4; ++r) {
      int qloc2 = w * 16 + hi * 4 + r;
      int hd = n * 16 + l15;
      oattn[obase + (size_t)qloc2 * DIM + hd] = (f16)(o[n][r] * invr[r]);
    }
}

// ---------------- GO: out = oattn @ W_out + b_out, 128x128 tiles (fp32 out) ----------------
__global__ __launch_bounds__(256) void k_go(const f16* __restrict__ oattn,
                                            const f16* __restrict__ WoT,
                                            const float* __restrict__ bias,
                                            float* __restrict__ out) {
  __shared__ __align__(16) f16 sA[128 * 64];
  __shared__ __align__(16) f16 sB[128 * 64];
  int bx = blockIdx.x;                 // 1024: mt(128) x nt(8)
  int mt = bx & 127, nt = bx >> 7;
  int bm = mt << 7, bn = nt << 7;
  f32x4 acc[4][4];
  mm_core<false, false, 128, 128>(oattn, nullptr, DIM, WoT, nullptr, DIM, bm, bn, DIM,
                                  sA, nullptr, sB, nullptr, acc);
  const int t = threadIdx.x, lane = t & 63, w = t >> 6;
  const int wr = w >> 1, wc = w & 1, l15 = lane & 15, hi = lane >> 4;
#pragma unroll
  for (int m = 0; m < 4; ++m)
#pragma unroll
    for (int n = 0; n < 4; ++n)
#pragma unroll
      for (int r = 0; r < 4; ++r) {
        int row = bm + wr * 64 + m * 16 + hi * 4 + r;
        int col = bn + wc * 64 + n * 16 + l15;
        out[(size_t)row * DIM + col] = acc[m][n][r] + bias[col];
      }
}

extern "C" void kernel_launch(void* const* d_in, const int* in_sizes, int n_in,
                              void* d_out, int out_size, void* d_ws, size_t ws_size,
                              hipStream_t stream) {
  const float* x    = (const float*)d_in[0];
  const float* Wqkv = (const float*)d_in[1];
  const float* E    = (const float*)d_in[2];
  const float* Wout = (const float*)d_in[3];
  const float* bout = (const float*)d_in[4];
  float* out = (float*)d_out;

  char* p = (char*)d_ws;
  f16* Wph = (f16*)p;  p += (size_t)2 * 3 * DIM * DIM;   //  6.29 MB
  f16* Wpl = (f16*)p;  p += (size_t)2 * 3 * DIM * DIM;
  f16* WoT = (f16*)p;  p += (size_t)2 * DIM * DIM;
  f16* xh  = (f16*)p;  p += (size_t)2 * ROWS * DIM;      // 33.55 MB
  f16* xth = (f16*)p;  p += (size_t)2 * DIM * ROWS;      // 33.55 MB
  f16* q   = (f16*)p;  p += (size_t)2 * ROWS * DIM;      // 33.55 MB (no alias: k_mid runs xe2||gq)
  f16* Eth = (f16*)p;  p += (size_t)2 * KRNK * SEQ;
  f16* XEh = (f16*)p;  p += (size_t)2 * NB * KRNK * DIM;
  f16* kph = (f16*)p;  p += (size_t)2 * NB * KRNK * DIM;
  f16* vpt = (f16*)p;  p += (size_t)2 * NB * DIM * KRNK;
  f16* oattn = (f16*)p; p += (size_t)2 * ROWS * DIM;     // 33.55 MB
  float* XEp = (float*)p;  p += (size_t)4 * NSPLIT * NB * KRNK * DIM;  // 16.8 MB
  size_t need = (size_t)(p - (char*)d_ws);
  if (ws_size < need) return;

  // grid = 1024 (W) + 4096 (x: 256 rtiles x 16 ctiles) + 256 (E: 64 rtiles x 4 ctiles)
  k_prep_all<<<5376, 256, 0, stream>>>(Wqkv, Wout, x, E, Wph, Wpl, WoT, xh, xth, Eth);
  k_mid<<<1536, 256, 0, stream>>>(Eth, xth, XEp, xh, Wph, q);
  k_xered<<<(NB * KRNK * DIM / 4) / 256, 256, 0, stream>>>(XEp, XEh);
  k_t2<<<256, 256, 0, stream>>>(XEh, Wph, Wpl, kph, vpt);
  k_attn<<<64 * 64, 256, 0, stream>>>(q, kph, vpt, oattn);
  k_go<<<1024, 256, 0, stream>>>(oattn, WoT, bout, out);
}